// Round 3
// baseline (1746.707 us; speedup 1.0000x reference)
//
#include <hip/hip_runtime.h>
#include <hip/hip_bf16.h>
#include <hip/hip_fp16.h>
#include <math.h>

// Problem constants
constexpr int cB   = 2;
constexpr int cS   = 2048;
constexpr int cD   = 1024;
constexpr int cQH  = 16;
constexpr int cKVH = 4;
constexpr int cDH  = 64;
constexpr int cTOPK = 128;
constexpr int cM   = cB * cS;          // 4096 rows for all GEMMs
constexpr int cNB  = cS / 64;          // 32 j-blocks of 64
constexpr int cLSZ = 384;              // kept-list capacity (128 + tie slack)

// Attention tiling
constexpr int cTI  = 16;               // query rows per workgroup (= 16 waves)
constexpr int cSTR = 260;              // staging row stride in u32 (2-way banks)

typedef __attribute__((ext_vector_type(8))) short short8;
typedef __attribute__((ext_vector_type(4))) float floatx4;
typedef _Float16 half8 __attribute__((ext_vector_type(8)));

// fp32 -> bf16 round-to-nearest-even (no NaN inputs in this problem)
__device__ inline ushort f2bf(float f) {
    unsigned u = __float_as_uint(f);
    return (ushort)((u + 0x7FFFu + ((u >> 16) & 1u)) >> 16);
}

// ---------------------------------------------------------------------------
// Cast fp32 -> bf16 (raw ushort), n multiple of 4.
// ---------------------------------------------------------------------------
__global__ void cast_f32_bf16(const float* __restrict__ src,
                              ushort* __restrict__ dst, int n) {
    int i4 = (blockIdx.x * blockDim.x + threadIdx.x) * 4;
    if (i4 >= n) return;
    const float4 v = *(const float4*)(src + i4);
    ushort4 r;
    r.x = f2bf(v.x); r.y = f2bf(v.y); r.z = f2bf(v.z); r.w = f2bf(v.w);
    *(ushort4*)(dst + i4) = r;
}

// ---------------------------------------------------------------------------
// Cast fp32 -> f16 (raw ushort), n multiple of 4.
// ---------------------------------------------------------------------------
__global__ void cast_f32_f16(const float* __restrict__ src,
                             ushort* __restrict__ dst, int n) {
    int i4 = (blockIdx.x * blockDim.x + threadIdx.x) * 4;
    if (i4 >= n) return;
    const float4 v = *(const float4*)(src + i4);
    ushort4 r;
    r.x = __builtin_bit_cast(ushort, (_Float16)v.x);
    r.y = __builtin_bit_cast(ushort, (_Float16)v.y);
    r.z = __builtin_bit_cast(ushort, (_Float16)v.z);
    r.w = __builtin_bit_cast(ushort, (_Float16)v.w);
    *(ushort4*)(dst + i4) = r;
}

// ---------------------------------------------------------------------------
// MFMA bf16 GEMM: C[m][n] = sum_k A[m][k] * W[n][k]  (A @ W^T).
// 128x128 block tile, BK=32, 256 threads = 4 waves (2x2 of 64x64).
// ---------------------------------------------------------------------------
__global__ __launch_bounds__(256) void gemm_bf16_bt(
        const ushort* __restrict__ A, const ushort* __restrict__ W,
        float* __restrict__ C, int M, int N, int K) {
    __shared__ short As[4][128][8];
    __shared__ short Bs[4][128][8];

    const int tid  = threadIdx.x;
    const int lane = tid & 63;
    const int w    = tid >> 6;          // 0..3
    const int wm   = (w & 1) * 64;
    const int wn   = (w >> 1) * 64;
    const int m0   = blockIdx.y * 128;
    const int n0   = blockIdx.x * 128;

    const int quad = lane >> 4;
    const int l16  = lane & 15;

    floatx4 acc[4][4];
    #pragma unroll
    for (int mi = 0; mi < 4; ++mi)
        #pragma unroll
        for (int ni = 0; ni < 4; ++ni)
            acc[mi][ni] = (floatx4){0.f, 0.f, 0.f, 0.f};

    const int sr = tid >> 1;            // staging row 0..127
    const int sh = (tid & 1) * 2;       // k-chunk pair 0 or 2

    for (int k0 = 0; k0 < K; k0 += 32) {
        const ushort* sa = A + (size_t)(m0 + sr) * K + k0 + sh * 8;
        const short8 a0 = *(const short8*)sa;
        const short8 a1 = *(const short8*)(sa + 8);
        const ushort* sw = W + (size_t)(n0 + sr) * K + k0 + sh * 8;
        const short8 b0 = *(const short8*)sw;
        const short8 b1 = *(const short8*)(sw + 8);
        *(short8*)&As[sh][sr][0]     = a0;
        *(short8*)&As[sh + 1][sr][0] = a1;
        *(short8*)&Bs[sh][sr][0]     = b0;
        *(short8*)&Bs[sh + 1][sr][0] = b1;
        __syncthreads();

        short8 af[4], bf[4];
        #pragma unroll
        for (int mi = 0; mi < 4; ++mi)
            af[mi] = *(const short8*)&As[quad][wm + mi * 16 + l16][0];
        #pragma unroll
        for (int ni = 0; ni < 4; ++ni)
            bf[ni] = *(const short8*)&Bs[quad][wn + ni * 16 + l16][0];
        #pragma unroll
        for (int mi = 0; mi < 4; ++mi)
            #pragma unroll
            for (int ni = 0; ni < 4; ++ni)
                acc[mi][ni] = __builtin_amdgcn_mfma_f32_16x16x32_bf16(
                    af[mi], bf[ni], acc[mi][ni], 0, 0, 0);
        __syncthreads();
    }

    // D layout: col = lane&15, row = quad*4 + reg
    #pragma unroll
    for (int mi = 0; mi < 4; ++mi)
        #pragma unroll
        for (int ni = 0; ni < 4; ++ni)
            #pragma unroll
            for (int r = 0; r < 4; ++r) {
                const int row = m0 + wm + mi * 16 + quad * 4 + r;
                const int col = n0 + wn + ni * 16 + l16;
                C[(size_t)row * N + col] = acc[mi][ni][r];
            }
}

// ---------------------------------------------------------------------------
// RoPE + scale + cast to f16, out of place.
// src layout (B*S, H, DH) fp32; dst same layout, f16 bits in ushort.
// ---------------------------------------------------------------------------
__global__ void rope_cast_f16(const float* __restrict__ src,
                              ushort* __restrict__ dst, int H, int total,
                              float scale) {
    int idx = blockIdx.x * blockDim.x + threadIdx.x;
    if (idx >= total) return;
    const int d   = idx & 31;
    const int h   = (idx >> 5) % H;
    const int row = idx / (32 * H);
    const int s   = row % cS;
    const float inv_freq = powf(10000.0f, -(float)d / 32.0f);
    const float ang = (float)s * inv_freq;
    const float c  = cosf(ang);
    const float si = sinf(ang);
    const float* p = src + (size_t)row * H * cDH + (size_t)h * cDH;
    const float x1 = p[d];
    const float x2 = p[d + 32];
    const float r1 = (x1 * c - x2 * si) * scale;
    const float r2 = (x2 * c + x1 * si) * scale;
    ushort* o = dst + (size_t)row * H * cDH + (size_t)h * cDH;
    o[d]      = __builtin_bit_cast(ushort, (_Float16)r1);
    o[d + 32] = __builtin_bit_cast(ushort, (_Float16)r2);
}

// ---------------------------------------------------------------------------
// Order-preserving float <-> uint bit maps (no NaNs here).
// ---------------------------------------------------------------------------
__device__ inline unsigned fmap(float f) {
    unsigned u = __float_as_uint(f);
    return (u & 0x80000000u) ? ~u : (u | 0x80000000u);
}
__device__ inline float funmap(unsigned u) {
    unsigned v = (u & 0x80000000u) ? (u & 0x7FFFFFFFu) : ~u;
    return __uint_as_float(v);
}

// ---------------------------------------------------------------------------
// MFMA tile attention with exact top-k threshold.  (R14 -> R15 changes)
//
// R14 post-mortem: 131KB LDS score buffer -> 1 block/CU (37.7% occupancy);
// the latency-bound bisection chain needs waves, not a resident score matrix.
// R15: the per-wave key[32] REGISTER array is the score storage (as in the
// original wave kernel); LDS only stages the MFMA->per-row transpose in
// 256-key chunks (double-buffered 2x16x260 u32 = 33KB), and the kl/jl
// compaction lists ALIAS the dead staging region afterwards: LDS = 49KB.
// __launch_bounds__(1024, 8) caps VGPR at 64 -> 2 blocks/CU = 32 waves.
//
// Chunk loop (fully unrolled, uniform trip count per block):
//   wave wv computes key block jb16 = c*16+wv via 2 chained
//   mfma_f32_16x16x32_f16 (fragment layout identical to gemm_bf16_bt:
//   A/B row = lane&15, k = quad*8+e; D row = quad*4+r, col = lane&15),
//   fmap+causal folded into the epilogue store -> sync -> wave wv gathers
//   its row's 256 keys at jperm positions into key[c*4+jj] (compile-time
//   indices). Double buffer => one barrier per chunk is sufficient.
// Phase 2 (1 row per wave): proven exact path, unchanged:
//  - key[32] 1D fully unrolled (R5/R6: runtime-indexed -> scratch spill).
//  - no cross-half (>=32) shuffles on the critical chain (R10).
//  - permuted key ownership (R11): selection is permutation-invariant.
//  - 8 independent PV accumulator chains.
// Big-it tiles dispatched first (descending it) to avoid a straggler tail.
// ---------------------------------------------------------------------------
__global__ __launch_bounds__(1024, 8) void attn_tile_kernel(
        const ushort* __restrict__ qf, const ushort* __restrict__ kf,
        const ushort* __restrict__ vf, ushort* __restrict__ out) {
    extern __shared__ char smem[];
    unsigned* stg = (unsigned*)smem;               // [2][cTI][cSTR] staging
    unsigned* klA = (unsigned*)smem;               // aliases staging (later)
    int*      jlA = (int*)(klA + cTI * cLSZ);

    const int lane = threadIdx.x & 63;
    const int wv   = __builtin_amdgcn_readfirstlane(threadIdx.x >> 6); // 0..15

    // grid: 32 * 128 blocks; it descending so the biggest tiles start first
    const int x  = blockIdx.x;
    const int it = (cS / cTI - 1) - (x >> 5);   // 127..0
    const int bh = x & 31;
    const int h  = bh & 15;
    const int b  = bh >> 4;
    const int kvh = h >> 2;                     // h / (QH/KVH)
    const int i0  = it * cTI;

    const size_t bS = (size_t)b * cS;
    const int l16   = lane & 15;
    const int quad  = lane >> 4;
    const int jperm = ((lane & 3) << 4) + (lane >> 2);   // permuted ownership
    const int i     = i0 + wv;                  // this wave's query row

    // A-frags: q rows i0 + l16, dims quad*8..+7 and +32 (f16, pre-scaled)
    const ushort* qp = qf + ((bS + i0 + l16) * cQH + h) * cDH + quad * 8;
    const half8 a0h = __builtin_bit_cast(half8, *(const uint4*)qp);
    const half8 a1h = __builtin_bit_cast(half8, *(const uint4*)(qp + 32));

    // ---- chunked MFMA scores -> key[32] registers -------------------------
    // prefetch chunk 0's key block (validity is monotone in c per wave)
    uint4 pb0, pb1;
    if (wv <= it) {
        const ushort* kp = kf + ((bS + (wv << 4) + l16) * cKVH + kvh) * cDH + quad * 8;
        pb0 = *(const uint4*)kp;
        pb1 = *(const uint4*)(kp + 32);
    }

    unsigned key[cNB];
    #pragma unroll
    for (int jb = 0; jb < cNB; ++jb) key[jb] = 0u;

    const int nchunk = (it >> 4) + 1;           // 256-key chunks
    #pragma unroll
    for (int c = 0; c < 8; ++c) {
        if (c >= nchunk) break;                 // uniform branch
        const int  jb16  = (c << 4) + wv;
        const bool valid = (jb16 <= it);
        const uint4 b0 = pb0, b1 = pb1;
        const int jn16 = ((c + 1) << 4) + wv;
        if (jn16 <= it) {                       // prefetch next chunk's block
            const ushort* kp = kf + ((bS + (jn16 << 4) + l16) * cKVH + kvh) * cDH + quad * 8;
            pb0 = *(const uint4*)kp;
            pb1 = *(const uint4*)(kp + 32);
        }
        if (valid) {
            floatx4 acc = (floatx4){0.f, 0.f, 0.f, 0.f};
            acc = __builtin_amdgcn_mfma_f32_16x16x32_f16(
                a0h, __builtin_bit_cast(half8, b0), acc, 0, 0, 0);
            acc = __builtin_amdgcn_mfma_f32_16x16x32_f16(
                a1h, __builtin_bit_cast(half8, b1), acc, 0, 0, 0);
            // D: row = quad*4 + r2 (q row in tile), col = l16 (key in block)
            const int col = (wv << 4) + l16;    // col within chunk
            const int jg  = (c << 8) + col;     // global key index
            unsigned* sp = stg + (c & 1) * (cTI * cSTR) + col;
            #pragma unroll
            for (int r2 = 0; r2 < 4; ++r2) {
                const int qrow = quad * 4 + r2;
                sp[qrow * cSTR] = (jg <= i0 + qrow) ? fmap(acc[r2]) : 0u;
            }
        }
        __syncthreads();
        // gather my row's 256 keys at jperm positions (2-way banks: free)
        {
            const unsigned* rp = stg + (c & 1) * (cTI * cSTR) + wv * cSTR;
            #pragma unroll
            for (int jj = 0; jj < 4; ++jj) {
                const int j = (c << 8) + (jj << 6) + jperm;
                const unsigned kr = rp[(jj << 6) + jperm];
                key[(c << 2) + jj] = (j <= i) ? kr : 0u;
            }
        }
        // double buffer: next iteration stores to the other half; its barrier
        // orders those stores after this chunk's reads. No second sync needed.
    }
    __syncthreads();   // staging dead; kl/jl lists may now clobber it

    // ---- Phase 2: per-row exact top-k + softmax + PV (1 row per wave) -----
    const int nb = (i >> 6) + 1;
    unsigned* kl = klA + wv * cLSZ;
    int*      jl = jlA + wv * cLSZ;
    const int vbase0 = (int)(((unsigned)bS * cKVH + kvh) * cDH);

    // row max + min over valid keys (valid keys are never 0)
    unsigned um = 0u, un = 0xFFFFFFFFu;
    #pragma unroll
    for (int jb = 0; jb < cNB; ++jb) {
        if (jb >= nb) break;
        const unsigned kk = key[jb];
        um = max(um, kk);
        un = min(un, kk ? kk : 0xFFFFFFFFu);
    }
    #pragma unroll
    for (int off = 32; off >= 1; off >>= 1) {
        um = max(um, (unsigned)__shfl_xor((int)um, off));
        un = min(un, (unsigned)__shfl_xor((int)un, off));
    }
    const float mrow = funmap(um);

    // exact 128th-largest key via bisection in [un, um]
    unsigned lo = un, hi = um;
    while (lo < hi) {
        const unsigned d   = hi - lo;
        const unsigned mid = lo + (d >> 1) + (d & 1u);
        int cnt2 = 0;
        #pragma unroll
        for (int jb = 0; jb < cNB; ++jb) {
            if (jb >= nb) break;
            cnt2 += __popcll(__ballot(key[jb] >= mid));
        }
        if (cnt2 >= cTOPK) lo = mid; else hi = mid - 1u;
    }
    const unsigned ustar = lo;

    // ballot-prefix compaction of kept (j, key) into LDS
    const unsigned long long mlt = (1ull << lane) - 1ull;
    int base = 0;
    #pragma unroll
    for (int jb = 0; jb < cNB; ++jb) {
        if (jb >= nb) break;
        const int j = (jb << 6) + jperm;
        const bool keep = (j <= i) && (key[jb] >= ustar);
        const unsigned long long mk = __ballot(keep);
        const int pos = base + __popcll(mk & mlt);
        if (keep && pos < cLSZ) {
            kl[pos] = key[jb];
            jl[pos] = vbase0 + j * (cKVH * cDH);   // v element offset
        }
        base += __popcll(mk);
    }
    const int cnt = min(base, cLSZ);

    // weights + Z
    float zp = 0.f;
    for (int t = lane; t < cnt; t += 64) {
        const float s  = funmap(kl[t]);
        const float wt = __expf(s - mrow);
        ((float*)kl)[t] = wt;
        zp += wt;
    }
    #pragma unroll
    for (int off = 32; off >= 1; off >>= 1) zp += __shfl_xor(zp, off);
    const float invZ = 1.0f / zp;

    // PV: lane = d, f16 v, 8 independent accumulator chains
    float ac0 = 0.f, ac1 = 0.f, ac2 = 0.f, ac3 = 0.f;
    float ac4 = 0.f, ac5 = 0.f, ac6 = 0.f, ac7 = 0.f;
    int t = 0;
    for (; t + 7 < cnt; t += 8) {
        const float wt0 = ((float*)kl)[t];
        const float wt1 = ((float*)kl)[t + 1];
        const float wt2 = ((float*)kl)[t + 2];
        const float wt3 = ((float*)kl)[t + 3];
        const float wt4 = ((float*)kl)[t + 4];
        const float wt5 = ((float*)kl)[t + 5];
        const float wt6 = ((float*)kl)[t + 6];
        const float wt7 = ((float*)kl)[t + 7];
        const int vo0 = jl[t];
        const int vo1 = jl[t + 1];
        const int vo2 = jl[t + 2];
        const int vo3 = jl[t + 3];
        const int vo4 = jl[t + 4];
        const int vo5 = jl[t + 5];
        const int vo6 = jl[t + 6];
        const int vo7 = jl[t + 7];
        ac0 += wt0 * (float)__builtin_bit_cast(_Float16, vf[vo0 + lane]);
        ac1 += wt1 * (float)__builtin_bit_cast(_Float16, vf[vo1 + lane]);
        ac2 += wt2 * (float)__builtin_bit_cast(_Float16, vf[vo2 + lane]);
        ac3 += wt3 * (float)__builtin_bit_cast(_Float16, vf[vo3 + lane]);
        ac4 += wt4 * (float)__builtin_bit_cast(_Float16, vf[vo4 + lane]);
        ac5 += wt5 * (float)__builtin_bit_cast(_Float16, vf[vo5 + lane]);
        ac6 += wt6 * (float)__builtin_bit_cast(_Float16, vf[vo6 + lane]);
        ac7 += wt7 * (float)__builtin_bit_cast(_Float16, vf[vo7 + lane]);
    }
    for (; t < cnt; ++t) {
        const float wt = ((float*)kl)[t];
        const int   vo = jl[t];
        ac0 += wt * (float)__builtin_bit_cast(_Float16, vf[vo + lane]);
    }
    const float acc = ((ac0 + ac1) + (ac2 + ac3)) + ((ac4 + ac5) + (ac6 + ac7));
    out[((bS + i) * cQH + h) * cDH + lane] = f2bf(acc * invZ);
}

// ---------------------------------------------------------------------------
// Launch
// ---------------------------------------------------------------------------
extern "C" void kernel_launch(void* const* d_in, const int* in_sizes, int n_in,
                              void* d_out, int out_size, void* d_ws, size_t ws_size,
                              hipStream_t stream) {
    const float* x  = (const float*)d_in[0];
    const float* Wq = (const float*)d_in[1];
    const float* Wk = (const float*)d_in[2];
    const float* Wv = (const float*)d_in[3];
    const float* Wo = (const float*)d_in[4];
    float* out = (float*)d_out;

    float* ws = (float*)d_ws;
    float*  qb  = ws;                                   // 4M f32 (B,S,QH,DH)
    float*  kb  = qb + (size_t)cM * cQH * cDH;          // 1M f32
    float*  vb  = kb + (size_t)cM * cKVH * cDH;         // 1M f32
    ushort* xh  = (ushort*)(vb + (size_t)cM * cKVH * cDH);  // 4M bf16
    ushort* Wqh = xh  + (size_t)cM * cD;                // 1M bf16
    ushort* Wkh = Wqh + (size_t)cQH * cDH * cD;         // 256K bf16
    ushort* Wvh = Wkh + (size_t)cKVH * cDH * cD;        // 256K bf16
    ushort* Woh = Wvh + (size_t)cKVH * cDH * cD;        // 1M bf16
    ushort* abh = Woh + (size_t)cD * cQH * cDH;         // 4M bf16
    ushort* kff = abh + (size_t)cM * cQH * cDH;         // 1M f16 (roped k)
    ushort* qff = kff + (size_t)cM * cKVH * cDH;        // 4M f16 (roped q/8)
    // f16 v aliased into kb's fp32 slot (kb is dead after its rope_cast)
    ushort* vff = (ushort*)kb;                          // 1M f16

    dim3 blk(256);

    // casts to bf16 (GEMM inputs)
    {
        const int nx  = cM * cD;
        const int nwq = cQH * cDH * cD;
        const int nwk = cKVH * cDH * cD;
        const int nwo = cD * cQH * cDH;
        cast_f32_bf16<<<(nx / 4 + 255) / 256, blk, 0, stream>>>(x, xh, nx);
        cast_f32_bf16<<<(nwq / 4 + 255) / 256, blk, 0, stream>>>(Wq, Wqh, nwq);
        cast_f32_bf16<<<(nwk / 4 + 255) / 256, blk, 0, stream>>>(Wk, Wkh, nwk);
        cast_f32_bf16<<<(nwk / 4 + 255) / 256, blk, 0, stream>>>(Wv, Wvh, nwk);
        cast_f32_bf16<<<(nwo / 4 + 255) / 256, blk, 0, stream>>>(Wo, Woh, nwo);
    }

    // QKV projections (bf16 MFMA, fp32 out)
    gemm_bf16_bt<<<dim3((cQH * cDH) / 128, cM / 128), blk, 0, stream>>>(xh, Wqh, qb, cM, cQH * cDH, cD);
    gemm_bf16_bt<<<dim3((cKVH * cDH) / 128, cM / 128), blk, 0, stream>>>(xh, Wkh, kb, cM, cKVH * cDH, cD);
    gemm_bf16_bt<<<dim3((cKVH * cDH) / 128, cM / 128), blk, 0, stream>>>(xh, Wvh, vb, cM, cKVH * cDH, cD);

    // Fused RoPE + cast to f16 (q pre-scaled by 1/sqrt(DH)); v cast to f16.
    // NOTE: v cast runs after k's rope_cast so reusing kb's space is safe
    // (same stream => ordered).
    {
        int totq = cM * cQH * 32;
        int totk = cM * cKVH * 32;
        rope_cast_f16<<<(totq + 255) / 256, blk, 0, stream>>>(qb, qff, cQH, totq, 0.125f);
        rope_cast_f16<<<(totk + 255) / 256, blk, 0, stream>>>(kb, kff, cKVH, totk, 1.0f);
        const int nv = cM * cKVH * cDH;
        cast_f32_f16<<<(nv / 4 + 255) / 256, blk, 0, stream>>>(vb, vff, nv);
    }

    // Attention: MFMA chunked-transpose kernel.
    // LDS = lists (16*384*8 = 49152 B); 33280 B staging aliases the same
    // region during the chunk loop. <= 64KB so no attribute opt-in needed.
    constexpr size_t aSMEM = (size_t)cTI * cLSZ * 8;    // 49152 B
    static_assert(2 * cTI * cSTR * 4 <= (int)aSMEM, "staging must fit");
    attn_tile_kernel<<<dim3((cB * cQH) * (cS / cTI)), dim3(1024), aSMEM, stream>>>(
        qff, kff, vff, abh);

    // Output projection (bf16 MFMA, fp32 out)
    gemm_bf16_bt<<<dim3(cD / 128, cM / 128), blk, 0, stream>>>(abh, Woh, out, cM, cD, cD);
}

// Round 4
// 749.278 us; speedup vs baseline: 2.3312x; 2.3312x over previous
//
#include <hip/hip_runtime.h>
#include <hip/hip_bf16.h>
#include <hip/hip_fp16.h>
#include <math.h>

// Problem constants
constexpr int cB   = 2;
constexpr int cS   = 2048;
constexpr int cD   = 1024;
constexpr int cQH  = 16;
constexpr int cKVH = 4;
constexpr int cDH  = 64;
constexpr int cTOPK = 128;
constexpr int cM   = cB * cS;          // 4096 rows for all GEMMs
constexpr int cNB  = cS / 64;          // 32 j-blocks of 64
constexpr int cLSZ = 384;              // kept-list capacity (128 + tie slack)

// Attention tiling (R16): 8 rows / 8 waves / 512 threads per block
constexpr int cTI  = 8;                // query rows per workgroup (= 8 waves)
constexpr int cSTR = 130;              // staging row stride in u32 (128 + pad)

typedef __attribute__((ext_vector_type(8))) short short8;
typedef __attribute__((ext_vector_type(4))) float floatx4;
typedef _Float16 half8 __attribute__((ext_vector_type(8)));

// fp32 -> bf16 round-to-nearest-even (no NaN inputs in this problem)
__device__ inline ushort f2bf(float f) {
    unsigned u = __float_as_uint(f);
    return (ushort)((u + 0x7FFFu + ((u >> 16) & 1u)) >> 16);
}

// ---------------------------------------------------------------------------
// Cast fp32 -> bf16 (raw ushort), n multiple of 4.
// ---------------------------------------------------------------------------
__global__ void cast_f32_bf16(const float* __restrict__ src,
                              ushort* __restrict__ dst, int n) {
    int i4 = (blockIdx.x * blockDim.x + threadIdx.x) * 4;
    if (i4 >= n) return;
    const float4 v = *(const float4*)(src + i4);
    ushort4 r;
    r.x = f2bf(v.x); r.y = f2bf(v.y); r.z = f2bf(v.z); r.w = f2bf(v.w);
    *(ushort4*)(dst + i4) = r;
}

// ---------------------------------------------------------------------------
// Cast fp32 -> f16 (raw ushort), n multiple of 4.
// ---------------------------------------------------------------------------
__global__ void cast_f32_f16(const float* __restrict__ src,
                             ushort* __restrict__ dst, int n) {
    int i4 = (blockIdx.x * blockDim.x + threadIdx.x) * 4;
    if (i4 >= n) return;
    const float4 v = *(const float4*)(src + i4);
    ushort4 r;
    r.x = __builtin_bit_cast(ushort, (_Float16)v.x);
    r.y = __builtin_bit_cast(ushort, (_Float16)v.y);
    r.z = __builtin_bit_cast(ushort, (_Float16)v.z);
    r.w = __builtin_bit_cast(ushort, (_Float16)v.w);
    *(ushort4*)(dst + i4) = r;
}

// ---------------------------------------------------------------------------
// MFMA bf16 GEMM: C[m][n] = sum_k A[m][k] * W[n][k]  (A @ W^T).
// 128x128 block tile, BK=32, 256 threads = 4 waves (2x2 of 64x64).
// ---------------------------------------------------------------------------
__global__ __launch_bounds__(256) void gemm_bf16_bt(
        const ushort* __restrict__ A, const ushort* __restrict__ W,
        float* __restrict__ C, int M, int N, int K) {
    __shared__ short As[4][128][8];
    __shared__ short Bs[4][128][8];

    const int tid  = threadIdx.x;
    const int lane = tid & 63;
    const int w    = tid >> 6;          // 0..3
    const int wm   = (w & 1) * 64;
    const int wn   = (w >> 1) * 64;
    const int m0   = blockIdx.y * 128;
    const int n0   = blockIdx.x * 128;

    const int quad = lane >> 4;
    const int l16  = lane & 15;

    floatx4 acc[4][4];
    #pragma unroll
    for (int mi = 0; mi < 4; ++mi)
        #pragma unroll
        for (int ni = 0; ni < 4; ++ni)
            acc[mi][ni] = (floatx4){0.f, 0.f, 0.f, 0.f};

    const int sr = tid >> 1;            // staging row 0..127
    const int sh = (tid & 1) * 2;       // k-chunk pair 0 or 2

    for (int k0 = 0; k0 < K; k0 += 32) {
        const ushort* sa = A + (size_t)(m0 + sr) * K + k0 + sh * 8;
        const short8 a0 = *(const short8*)sa;
        const short8 a1 = *(const short8*)(sa + 8);
        const ushort* sw = W + (size_t)(n0 + sr) * K + k0 + sh * 8;
        const short8 b0 = *(const short8*)sw;
        const short8 b1 = *(const short8*)(sw + 8);
        *(short8*)&As[sh][sr][0]     = a0;
        *(short8*)&As[sh + 1][sr][0] = a1;
        *(short8*)&Bs[sh][sr][0]     = b0;
        *(short8*)&Bs[sh + 1][sr][0] = b1;
        __syncthreads();

        short8 af[4], bf[4];
        #pragma unroll
        for (int mi = 0; mi < 4; ++mi)
            af[mi] = *(const short8*)&As[quad][wm + mi * 16 + l16][0];
        #pragma unroll
        for (int ni = 0; ni < 4; ++ni)
            bf[ni] = *(const short8*)&Bs[quad][wn + ni * 16 + l16][0];
        #pragma unroll
        for (int mi = 0; mi < 4; ++mi)
            #pragma unroll
            for (int ni = 0; ni < 4; ++ni)
                acc[mi][ni] = __builtin_amdgcn_mfma_f32_16x16x32_bf16(
                    af[mi], bf[ni], acc[mi][ni], 0, 0, 0);
        __syncthreads();
    }

    // D layout: col = lane&15, row = quad*4 + reg
    #pragma unroll
    for (int mi = 0; mi < 4; ++mi)
        #pragma unroll
        for (int ni = 0; ni < 4; ++ni)
            #pragma unroll
            for (int r = 0; r < 4; ++r) {
                const int row = m0 + wm + mi * 16 + quad * 4 + r;
                const int col = n0 + wn + ni * 16 + l16;
                C[(size_t)row * N + col] = acc[mi][ni][r];
            }
}

// ---------------------------------------------------------------------------
// RoPE + scale + cast to f16, out of place.
// src layout (B*S, H, DH) fp32; dst same layout, f16 bits in ushort.
// ---------------------------------------------------------------------------
__global__ void rope_cast_f16(const float* __restrict__ src,
                              ushort* __restrict__ dst, int H, int total,
                              float scale) {
    int idx = blockIdx.x * blockDim.x + threadIdx.x;
    if (idx >= total) return;
    const int d   = idx & 31;
    const int h   = (idx >> 5) % H;
    const int row = idx / (32 * H);
    const int s   = row % cS;
    const float inv_freq = powf(10000.0f, -(float)d / 32.0f);
    const float ang = (float)s * inv_freq;
    const float c  = cosf(ang);
    const float si = sinf(ang);
    const float* p = src + (size_t)row * H * cDH + (size_t)h * cDH;
    const float x1 = p[d];
    const float x2 = p[d + 32];
    const float r1 = (x1 * c - x2 * si) * scale;
    const float r2 = (x2 * c + x1 * si) * scale;
    ushort* o = dst + (size_t)row * H * cDH + (size_t)h * cDH;
    o[d]      = __builtin_bit_cast(ushort, (_Float16)r1);
    o[d + 32] = __builtin_bit_cast(ushort, (_Float16)r2);
}

// ---------------------------------------------------------------------------
// Order-preserving float <-> uint bit maps (no NaNs here).
// ---------------------------------------------------------------------------
__device__ inline unsigned fmap(float f) {
    unsigned u = __float_as_uint(f);
    return (u & 0x80000000u) ? ~u : (u | 0x80000000u);
}
__device__ inline float funmap(unsigned u) {
    unsigned v = (u & 0x80000000u) ? (u & 0x7FFFFFFFu) : ~u;
    return __uint_as_float(v);
}

// ---------------------------------------------------------------------------
// MFMA tile attention with exact top-k threshold.  (R15 -> R16 changes)
//
// R15 post-mortem: __launch_bounds__(1024,8) capped unified VGPR+AGPR at 64;
// key[32] spilled to SCRATCH -> 3.8 GB HBM traffic/dispatch, 2x slower.
// R16: natural register allocation (no min-waves bound). 512 threads =
// 8 waves, cTI=8 rows, 1 row/wave. LDS = 24 KB (kl/jl lists, staging
// aliased) -> occupancy limited by regs at ~2-3 blocks/CU instead of R14's
// hard 1-block/1024-thread quantization.
//
// Phase 1 (chunked MFMA scores -> key[32] registers): per chunk c, wave wv
// computes 16-key block kb16 = c*8+wv via 2 chained mfma_f32_16x16x32_f16.
// A-frag holds the block's 8 q-rows duplicated (row = l16&7); D rows 8..15
// are duplicates, so only quads 0/1 store (half of an idle MFMA pipe is
// free).  fmap+causal folded into the store.  Double-buffered staging
// [2][8][130] u32; one barrier per chunk; wave wv gathers its row's keys at
// jperm positions into key[c*2+jj] (compile-time indices).
// Phase 2 (1 row per wave): proven exact path, unchanged:
//  - key[32] 1D fully unrolled (R5/R6: runtime-indexed -> scratch spill).
//  - no cross-half (>=32) shuffles on the critical chain (R10).
//  - permuted key ownership (R11): selection is permutation-invariant.
//  - 8 independent PV accumulator chains.
// Big-it tiles dispatched first (descending it) to avoid a straggler tail.
// ---------------------------------------------------------------------------
__global__ __launch_bounds__(512) void attn_tile_kernel(
        const ushort* __restrict__ qf, const ushort* __restrict__ kf,
        const ushort* __restrict__ vf, ushort* __restrict__ out) {
    extern __shared__ char smem[];
    unsigned* stg = (unsigned*)smem;               // [2][cTI][cSTR] staging
    unsigned* klA = (unsigned*)smem;               // aliases staging (later)
    int*      jlA = (int*)(klA + cTI * cLSZ);

    const int lane = threadIdx.x & 63;
    const int wv   = __builtin_amdgcn_readfirstlane(threadIdx.x >> 6); // 0..7

    // grid: 32 * 256 blocks; it descending so the biggest tiles start first
    const int x  = blockIdx.x;
    const int it = (cS / cTI - 1) - (x >> 5);   // 255..0
    const int bh = x & 31;
    const int h  = bh & 15;
    const int b  = bh >> 4;
    const int kvh = h >> 2;                     // h / (QH/KVH)
    const int i0  = it * cTI;

    const size_t bS = (size_t)b * cS;
    const int l16   = lane & 15;
    const int quad  = lane >> 4;
    const int jperm = ((lane & 3) << 4) + (lane >> 2);   // permuted ownership
    const int i     = i0 + wv;                  // this wave's query row

    // A-frags: q rows i0 + (l16&7) (rows 8..15 duplicate), dims quad*8..+7
    // and +32 (f16, pre-scaled by 1/sqrt(DH))
    const ushort* qp = qf + ((bS + i0 + (l16 & 7)) * cQH + h) * cDH + quad * 8;
    const half8 a0h = __builtin_bit_cast(half8, *(const uint4*)qp);
    const half8 a1h = __builtin_bit_cast(half8, *(const uint4*)(qp + 32));

    unsigned key[cNB];
    #pragma unroll
    for (int jb = 0; jb < cNB; ++jb) key[jb] = 0u;

    const int nk16   = ((i0 + cTI - 1) >> 4) + 1;   // 16-key blocks needed
    const int nchunk = (nk16 + 7) >> 3;             // 128-key chunks

    #pragma unroll
    for (int c = 0; c < 16; ++c) {
        if (c >= nchunk) break;                 // block-uniform branch
        const int  kb16  = (c << 3) + wv;       // this wave's 16-key block
        if (kb16 < nk16) {
            const ushort* kp = kf + ((bS + (kb16 << 4) + l16) * cKVH + kvh) * cDH + quad * 8;
            const uint4 b0 = *(const uint4*)kp;
            const uint4 b1 = *(const uint4*)(kp + 32);
            floatx4 acc = (floatx4){0.f, 0.f, 0.f, 0.f};
            acc = __builtin_amdgcn_mfma_f32_16x16x32_f16(
                a0h, __builtin_bit_cast(half8, b0), acc, 0, 0, 0);
            acc = __builtin_amdgcn_mfma_f32_16x16x32_f16(
                a1h, __builtin_bit_cast(half8, b1), acc, 0, 0, 0);
            // D: row = quad*4 + r2, col = l16.  Rows 8..15 duplicate rows
            // 0..7 -> only quads 0/1 store.  fmap + causal mask folded in.
            if (quad < 2) {
                const int jg = (kb16 << 4) + l16;           // global key idx
                unsigned* sp = stg + (c & 1) * (cTI * cSTR) + (wv << 4) + l16;
                #pragma unroll
                for (int r2 = 0; r2 < 4; ++r2) {
                    const int qrow = quad * 4 + r2;         // 0..7
                    sp[qrow * cSTR] = (jg <= i0 + qrow) ? fmap(acc[r2]) : 0u;
                }
            }
        }
        __syncthreads();
        // gather my row's 128 chunk keys at jperm positions (<=2-way banks)
        {
            const unsigned* rp = stg + (c & 1) * (cTI * cSTR) + wv * cSTR;
            #pragma unroll
            for (int jj = 0; jj < 2; ++jj) {
                const int j = (c << 7) + (jj << 6) + jperm;
                const unsigned kr = rp[(jj << 6) + jperm];
                key[(c << 1) + jj] = (j <= i) ? kr : 0u;
            }
        }
        // double buffer: next chunk stores to the other half; its barrier
        // orders those stores after this chunk's reads.
    }
    __syncthreads();   // staging dead; kl/jl lists may now clobber it

    // ---- Phase 2: per-row exact top-k + softmax + PV (1 row per wave) -----
    const int nb = (i >> 6) + 1;
    unsigned* kl = klA + wv * cLSZ;
    int*      jl = jlA + wv * cLSZ;
    const int vbase0 = (int)(((unsigned)bS * cKVH + kvh) * cDH);

    // row max + min over valid keys (valid keys are never 0)
    unsigned um = 0u, un = 0xFFFFFFFFu;
    #pragma unroll
    for (int jb = 0; jb < cNB; ++jb) {
        if (jb >= nb) break;
        const unsigned kk = key[jb];
        um = max(um, kk);
        un = min(un, kk ? kk : 0xFFFFFFFFu);
    }
    #pragma unroll
    for (int off = 32; off >= 1; off >>= 1) {
        um = max(um, (unsigned)__shfl_xor((int)um, off));
        un = min(un, (unsigned)__shfl_xor((int)un, off));
    }
    const float mrow = funmap(um);

    // exact 128th-largest key via bisection in [un, um]
    unsigned lo = un, hi = um;
    while (lo < hi) {
        const unsigned d   = hi - lo;
        const unsigned mid = lo + (d >> 1) + (d & 1u);
        int cnt2 = 0;
        #pragma unroll
        for (int jb = 0; jb < cNB; ++jb) {
            if (jb >= nb) break;
            cnt2 += __popcll(__ballot(key[jb] >= mid));
        }
        if (cnt2 >= cTOPK) lo = mid; else hi = mid - 1u;
    }
    const unsigned ustar = lo;

    // ballot-prefix compaction of kept (j, key) into LDS
    const unsigned long long mlt = (1ull << lane) - 1ull;
    int base = 0;
    #pragma unroll
    for (int jb = 0; jb < cNB; ++jb) {
        if (jb >= nb) break;
        const int j = (jb << 6) + jperm;
        const bool keep = (j <= i) && (key[jb] >= ustar);
        const unsigned long long mk = __ballot(keep);
        const int pos = base + __popcll(mk & mlt);
        if (keep && pos < cLSZ) {
            kl[pos] = key[jb];
            jl[pos] = vbase0 + j * (cKVH * cDH);   // v element offset
        }
        base += __popcll(mk);
    }
    const int cnt = min(base, cLSZ);

    // weights + Z
    float zp = 0.f;
    for (int t = lane; t < cnt; t += 64) {
        const float s  = funmap(kl[t]);
        const float wt = __expf(s - mrow);
        ((float*)kl)[t] = wt;
        zp += wt;
    }
    #pragma unroll
    for (int off = 32; off >= 1; off >>= 1) zp += __shfl_xor(zp, off);
    const float invZ = 1.0f / zp;

    // PV: lane = d, f16 v, 8 independent accumulator chains
    float ac0 = 0.f, ac1 = 0.f, ac2 = 0.f, ac3 = 0.f;
    float ac4 = 0.f, ac5 = 0.f, ac6 = 0.f, ac7 = 0.f;
    int t = 0;
    for (; t + 7 < cnt; t += 8) {
        const float wt0 = ((float*)kl)[t];
        const float wt1 = ((float*)kl)[t + 1];
        const float wt2 = ((float*)kl)[t + 2];
        const float wt3 = ((float*)kl)[t + 3];
        const float wt4 = ((float*)kl)[t + 4];
        const float wt5 = ((float*)kl)[t + 5];
        const float wt6 = ((float*)kl)[t + 6];
        const float wt7 = ((float*)kl)[t + 7];
        const int vo0 = jl[t];
        const int vo1 = jl[t + 1];
        const int vo2 = jl[t + 2];
        const int vo3 = jl[t + 3];
        const int vo4 = jl[t + 4];
        const int vo5 = jl[t + 5];
        const int vo6 = jl[t + 6];
        const int vo7 = jl[t + 7];
        ac0 += wt0 * (float)__builtin_bit_cast(_Float16, vf[vo0 + lane]);
        ac1 += wt1 * (float)__builtin_bit_cast(_Float16, vf[vo1 + lane]);
        ac2 += wt2 * (float)__builtin_bit_cast(_Float16, vf[vo2 + lane]);
        ac3 += wt3 * (float)__builtin_bit_cast(_Float16, vf[vo3 + lane]);
        ac4 += wt4 * (float)__builtin_bit_cast(_Float16, vf[vo4 + lane]);
        ac5 += wt5 * (float)__builtin_bit_cast(_Float16, vf[vo5 + lane]);
        ac6 += wt6 * (float)__builtin_bit_cast(_Float16, vf[vo6 + lane]);
        ac7 += wt7 * (float)__builtin_bit_cast(_Float16, vf[vo7 + lane]);
    }
    for (; t < cnt; ++t) {
        const float wt = ((float*)kl)[t];
        const int   vo = jl[t];
        ac0 += wt * (float)__builtin_bit_cast(_Float16, vf[vo + lane]);
    }
    const float acc = ((ac0 + ac1) + (ac2 + ac3)) + ((ac4 + ac5) + (ac6 + ac7));
    out[((bS + i) * cQH + h) * cDH + lane] = f2bf(acc * invZ);
}

// ---------------------------------------------------------------------------
// Launch
// ---------------------------------------------------------------------------
extern "C" void kernel_launch(void* const* d_in, const int* in_sizes, int n_in,
                              void* d_out, int out_size, void* d_ws, size_t ws_size,
                              hipStream_t stream) {
    const float* x  = (const float*)d_in[0];
    const float* Wq = (const float*)d_in[1];
    const float* Wk = (const float*)d_in[2];
    const float* Wv = (const float*)d_in[3];
    const float* Wo = (const float*)d_in[4];
    float* out = (float*)d_out;

    float* ws = (float*)d_ws;
    float*  qb  = ws;                                   // 4M f32 (B,S,QH,DH)
    float*  kb  = qb + (size_t)cM * cQH * cDH;          // 1M f32
    float*  vb  = kb + (size_t)cM * cKVH * cDH;         // 1M f32
    ushort* xh  = (ushort*)(vb + (size_t)cM * cKVH * cDH);  // 4M bf16
    ushort* Wqh = xh  + (size_t)cM * cD;                // 1M bf16
    ushort* Wkh = Wqh + (size_t)cQH * cDH * cD;         // 256K bf16
    ushort* Wvh = Wkh + (size_t)cKVH * cDH * cD;        // 256K bf16
    ushort* Woh = Wvh + (size_t)cKVH * cDH * cD;        // 1M bf16
    ushort* abh = Woh + (size_t)cD * cQH * cDH;         // 4M bf16
    ushort* kff = abh + (size_t)cM * cQH * cDH;         // 1M f16 (roped k)
    ushort* qff = kff + (size_t)cM * cKVH * cDH;        // 4M f16 (roped q/8)
    // f16 v aliased into kb's fp32 slot (kb is dead after its rope_cast)
    ushort* vff = (ushort*)kb;                          // 1M f16

    dim3 blk(256);

    // casts to bf16 (GEMM inputs)
    {
        const int nx  = cM * cD;
        const int nwq = cQH * cDH * cD;
        const int nwk = cKVH * cDH * cD;
        const int nwo = cD * cQH * cDH;
        cast_f32_bf16<<<(nx / 4 + 255) / 256, blk, 0, stream>>>(x, xh, nx);
        cast_f32_bf16<<<(nwq / 4 + 255) / 256, blk, 0, stream>>>(Wq, Wqh, nwq);
        cast_f32_bf16<<<(nwk / 4 + 255) / 256, blk, 0, stream>>>(Wk, Wkh, nwk);
        cast_f32_bf16<<<(nwk / 4 + 255) / 256, blk, 0, stream>>>(Wv, Wvh, nwk);
        cast_f32_bf16<<<(nwo / 4 + 255) / 256, blk, 0, stream>>>(Wo, Woh, nwo);
    }

    // QKV projections (bf16 MFMA, fp32 out)
    gemm_bf16_bt<<<dim3((cQH * cDH) / 128, cM / 128), blk, 0, stream>>>(xh, Wqh, qb, cM, cQH * cDH, cD);
    gemm_bf16_bt<<<dim3((cKVH * cDH) / 128, cM / 128), blk, 0, stream>>>(xh, Wkh, kb, cM, cKVH * cDH, cD);
    gemm_bf16_bt<<<dim3((cKVH * cDH) / 128, cM / 128), blk, 0, stream>>>(xh, Wvh, vb, cM, cKVH * cDH, cD);

    // Fused RoPE + cast to f16 (q pre-scaled by 1/sqrt(DH)); v cast to f16.
    // NOTE: v cast runs after k's rope_cast so reusing kb's space is safe
    // (same stream => ordered).
    {
        int totq = cM * cQH * 32;
        int totk = cM * cKVH * 32;
        rope_cast_f16<<<(totq + 255) / 256, blk, 0, stream>>>(qb, qff, cQH, totq, 0.125f);
        rope_cast_f16<<<(totk + 255) / 256, blk, 0, stream>>>(kb, kff, cKVH, totk, 1.0f);
        const int nv = cM * cKVH * cDH;
        cast_f32_f16<<<(nv / 4 + 255) / 256, blk, 0, stream>>>(vb, vff, nv);
    }

    // Attention: MFMA chunked-transpose kernel, 512 threads, 24 KB LDS
    // (lists 8*384*8 = 24576 B; staging 2*8*130*4 = 8320 B aliases them).
    constexpr size_t aSMEM = (size_t)cTI * cLSZ * 8;    // 24576 B
    static_assert(2 * cTI * cSTR * 4 <= (int)aSMEM, "staging must fit");
    attn_tile_kernel<<<dim3(32 * (cS / cTI)), dim3(512), aSMEM, stream>>>(
        qff, kff, vff, abh);

    // Output projection (bf16 MFMA, fp32 out)
    gemm_bf16_bt<<<dim3(cD / 128, cM / 128), blk, 0, stream>>>(abh, Woh, out, cM, cD, cD);
}

// Round 5
// 587.992 us; speedup vs baseline: 2.9706x; 1.2743x over previous
//
#include <hip/hip_runtime.h>
#include <hip/hip_bf16.h>
#include <hip/hip_fp16.h>
#include <math.h>

// Problem constants
constexpr int cB   = 2;
constexpr int cS   = 2048;
constexpr int cD   = 1024;
constexpr int cQH  = 16;
constexpr int cKVH = 4;
constexpr int cDH  = 64;
constexpr int cTOPK = 128;
constexpr int cM   = cB * cS;          // 4096 rows for all GEMMs
constexpr int cNB  = cS / 64;          // 32 j-blocks of 64
constexpr int cLSZ = 384;              // kept-list capacity (128 + tie slack)

// Attention tiling (R16): 8 rows / 8 waves / 512 threads per block
constexpr int cTI  = 8;                // query rows per workgroup (= 8 waves)
constexpr int cSTR = 130;              // staging row stride in u32 (128 + pad)

typedef __attribute__((ext_vector_type(8))) short short8;
typedef __attribute__((ext_vector_type(4))) float floatx4;
typedef _Float16 half8 __attribute__((ext_vector_type(8)));

// fp32 -> bf16 round-to-nearest-even (no NaN inputs in this problem)
__device__ inline ushort f2bf(float f) {
    unsigned u = __float_as_uint(f);
    return (ushort)((u + 0x7FFFu + ((u >> 16) & 1u)) >> 16);
}

// ---------------------------------------------------------------------------
// Cast fp32 -> bf16 (raw ushort), n multiple of 4.
// ---------------------------------------------------------------------------
__global__ void cast_f32_bf16(const float* __restrict__ src,
                              ushort* __restrict__ dst, int n) {
    int i4 = (blockIdx.x * blockDim.x + threadIdx.x) * 4;
    if (i4 >= n) return;
    const float4 v = *(const float4*)(src + i4);
    ushort4 r;
    r.x = f2bf(v.x); r.y = f2bf(v.y); r.z = f2bf(v.z); r.w = f2bf(v.w);
    *(ushort4*)(dst + i4) = r;
}

// ---------------------------------------------------------------------------
// Cast fp32 -> f16 (raw ushort), n multiple of 4.
// ---------------------------------------------------------------------------
__global__ void cast_f32_f16(const float* __restrict__ src,
                             ushort* __restrict__ dst, int n) {
    int i4 = (blockIdx.x * blockDim.x + threadIdx.x) * 4;
    if (i4 >= n) return;
    const float4 v = *(const float4*)(src + i4);
    ushort4 r;
    r.x = __builtin_bit_cast(ushort, (_Float16)v.x);
    r.y = __builtin_bit_cast(ushort, (_Float16)v.y);
    r.z = __builtin_bit_cast(ushort, (_Float16)v.z);
    r.w = __builtin_bit_cast(ushort, (_Float16)v.w);
    *(ushort4*)(dst + i4) = r;
}

// ---------------------------------------------------------------------------
// MFMA bf16 GEMM: C[m][n] = sum_k A[m][k] * W[n][k]  (A @ W^T).
// 128x128 block tile, BK=32, 256 threads = 4 waves (2x2 of 64x64).
// ---------------------------------------------------------------------------
__global__ __launch_bounds__(256) void gemm_bf16_bt(
        const ushort* __restrict__ A, const ushort* __restrict__ W,
        float* __restrict__ C, int M, int N, int K) {
    __shared__ short As[4][128][8];
    __shared__ short Bs[4][128][8];

    const int tid  = threadIdx.x;
    const int lane = tid & 63;
    const int w    = tid >> 6;          // 0..3
    const int wm   = (w & 1) * 64;
    const int wn   = (w >> 1) * 64;
    const int m0   = blockIdx.y * 128;
    const int n0   = blockIdx.x * 128;

    const int quad = lane >> 4;
    const int l16  = lane & 15;

    floatx4 acc[4][4];
    #pragma unroll
    for (int mi = 0; mi < 4; ++mi)
        #pragma unroll
        for (int ni = 0; ni < 4; ++ni)
            acc[mi][ni] = (floatx4){0.f, 0.f, 0.f, 0.f};

    const int sr = tid >> 1;            // staging row 0..127
    const int sh = (tid & 1) * 2;       // k-chunk pair 0 or 2

    for (int k0 = 0; k0 < K; k0 += 32) {
        const ushort* sa = A + (size_t)(m0 + sr) * K + k0 + sh * 8;
        const short8 a0 = *(const short8*)sa;
        const short8 a1 = *(const short8*)(sa + 8);
        const ushort* sw = W + (size_t)(n0 + sr) * K + k0 + sh * 8;
        const short8 b0 = *(const short8*)sw;
        const short8 b1 = *(const short8*)(sw + 8);
        *(short8*)&As[sh][sr][0]     = a0;
        *(short8*)&As[sh + 1][sr][0] = a1;
        *(short8*)&Bs[sh][sr][0]     = b0;
        *(short8*)&Bs[sh + 1][sr][0] = b1;
        __syncthreads();

        short8 af[4], bf[4];
        #pragma unroll
        for (int mi = 0; mi < 4; ++mi)
            af[mi] = *(const short8*)&As[quad][wm + mi * 16 + l16][0];
        #pragma unroll
        for (int ni = 0; ni < 4; ++ni)
            bf[ni] = *(const short8*)&Bs[quad][wn + ni * 16 + l16][0];
        #pragma unroll
        for (int mi = 0; mi < 4; ++mi)
            #pragma unroll
            for (int ni = 0; ni < 4; ++ni)
                acc[mi][ni] = __builtin_amdgcn_mfma_f32_16x16x32_bf16(
                    af[mi], bf[ni], acc[mi][ni], 0, 0, 0);
        __syncthreads();
    }

    // D layout: col = lane&15, row = quad*4 + reg
    #pragma unroll
    for (int mi = 0; mi < 4; ++mi)
        #pragma unroll
        for (int ni = 0; ni < 4; ++ni)
            #pragma unroll
            for (int r = 0; r < 4; ++r) {
                const int row = m0 + wm + mi * 16 + quad * 4 + r;
                const int col = n0 + wn + ni * 16 + l16;
                C[(size_t)row * N + col] = acc[mi][ni][r];
            }
}

// ---------------------------------------------------------------------------
// RoPE + scale + cast to f16, out of place.
// src layout (B*S, H, DH) fp32; dst same layout, f16 bits in ushort.
// ---------------------------------------------------------------------------
__global__ void rope_cast_f16(const float* __restrict__ src,
                              ushort* __restrict__ dst, int H, int total,
                              float scale) {
    int idx = blockIdx.x * blockDim.x + threadIdx.x;
    if (idx >= total) return;
    const int d   = idx & 31;
    const int h   = (idx >> 5) % H;
    const int row = idx / (32 * H);
    const int s   = row % cS;
    const float inv_freq = powf(10000.0f, -(float)d / 32.0f);
    const float ang = (float)s * inv_freq;
    const float c  = cosf(ang);
    const float si = sinf(ang);
    const float* p = src + (size_t)row * H * cDH + (size_t)h * cDH;
    const float x1 = p[d];
    const float x2 = p[d + 32];
    const float r1 = (x1 * c - x2 * si) * scale;
    const float r2 = (x2 * c + x1 * si) * scale;
    ushort* o = dst + (size_t)row * H * cDH + (size_t)h * cDH;
    o[d]      = __builtin_bit_cast(ushort, (_Float16)r1);
    o[d + 32] = __builtin_bit_cast(ushort, (_Float16)r2);
}

// ---------------------------------------------------------------------------
// Order-preserving float <-> uint bit maps (no NaNs here).
// ---------------------------------------------------------------------------
__device__ inline unsigned fmap(float f) {
    unsigned u = __float_as_uint(f);
    return (u & 0x80000000u) ? ~u : (u | 0x80000000u);
}
__device__ inline float funmap(unsigned u) {
    unsigned v = (u & 0x80000000u) ? (u & 0x7FFFFFFFu) : ~u;
    return __uint_as_float(v);
}

// ---------------------------------------------------------------------------
// MFMA tile attention with exact top-k threshold.  (R16 -> R17 changes)
//
// R16 post-mortem: structure validated (no spill, occ 89%, attn 565us).
// Remaining cost: the 32-iteration value-space bisection is a serial
// dependency chain (~nb v_cmps per iter) = the dominant phase-2 latency.
// R17 (exactness-preserving):
//  1. EARLY-EXIT bisection: if count(>=mid) == 128 exactly, the threshold
//     is min{key >= mid} -> one predicated wave-min reduce finishes the
//     search (~12 iters typical instead of 32).  Ties fall through to the
//     full bisection (exact fallback).
//  2. rows with i < 128 keep all keys: ustar = un directly, no bisection.
//  3. PV loop: #pragma unroll 2 restored (R12-proven) -> 16 v-loads in
//     flight per body, halves exposed L2 latency.
// Everything else identical to R16.
// ---------------------------------------------------------------------------
__global__ __launch_bounds__(512) void attn_tile_kernel(
        const ushort* __restrict__ qf, const ushort* __restrict__ kf,
        const ushort* __restrict__ vf, ushort* __restrict__ out) {
    extern __shared__ char smem[];
    unsigned* stg = (unsigned*)smem;               // [2][cTI][cSTR] staging
    unsigned* klA = (unsigned*)smem;               // aliases staging (later)
    int*      jlA = (int*)(klA + cTI * cLSZ);

    const int lane = threadIdx.x & 63;
    const int wv   = __builtin_amdgcn_readfirstlane(threadIdx.x >> 6); // 0..7

    // grid: 32 * 256 blocks; it descending so the biggest tiles start first
    const int x  = blockIdx.x;
    const int it = (cS / cTI - 1) - (x >> 5);   // 255..0
    const int bh = x & 31;
    const int h  = bh & 15;
    const int b  = bh >> 4;
    const int kvh = h >> 2;                     // h / (QH/KVH)
    const int i0  = it * cTI;

    const size_t bS = (size_t)b * cS;
    const int l16   = lane & 15;
    const int quad  = lane >> 4;
    const int jperm = ((lane & 3) << 4) + (lane >> 2);   // permuted ownership
    const int i     = i0 + wv;                  // this wave's query row

    // A-frags: q rows i0 + (l16&7) (rows 8..15 duplicate), dims quad*8..+7
    // and +32 (f16, pre-scaled by 1/sqrt(DH))
    const ushort* qp = qf + ((bS + i0 + (l16 & 7)) * cQH + h) * cDH + quad * 8;
    const half8 a0h = __builtin_bit_cast(half8, *(const uint4*)qp);
    const half8 a1h = __builtin_bit_cast(half8, *(const uint4*)(qp + 32));

    unsigned key[cNB];
    #pragma unroll
    for (int jb = 0; jb < cNB; ++jb) key[jb] = 0u;

    const int nk16   = ((i0 + cTI - 1) >> 4) + 1;   // 16-key blocks needed
    const int nchunk = (nk16 + 7) >> 3;             // 128-key chunks

    #pragma unroll
    for (int c = 0; c < 16; ++c) {
        if (c >= nchunk) break;                 // block-uniform branch
        const int  kb16  = (c << 3) + wv;       // this wave's 16-key block
        if (kb16 < nk16) {
            const ushort* kp = kf + ((bS + (kb16 << 4) + l16) * cKVH + kvh) * cDH + quad * 8;
            const uint4 b0 = *(const uint4*)kp;
            const uint4 b1 = *(const uint4*)(kp + 32);
            floatx4 acc = (floatx4){0.f, 0.f, 0.f, 0.f};
            acc = __builtin_amdgcn_mfma_f32_16x16x32_f16(
                a0h, __builtin_bit_cast(half8, b0), acc, 0, 0, 0);
            acc = __builtin_amdgcn_mfma_f32_16x16x32_f16(
                a1h, __builtin_bit_cast(half8, b1), acc, 0, 0, 0);
            // D: row = quad*4 + r2, col = l16.  Rows 8..15 duplicate rows
            // 0..7 -> only quads 0/1 store.  fmap + causal mask folded in.
            if (quad < 2) {
                const int jg = (kb16 << 4) + l16;           // global key idx
                unsigned* sp = stg + (c & 1) * (cTI * cSTR) + (wv << 4) + l16;
                #pragma unroll
                for (int r2 = 0; r2 < 4; ++r2) {
                    const int qrow = quad * 4 + r2;         // 0..7
                    sp[qrow * cSTR] = (jg <= i0 + qrow) ? fmap(acc[r2]) : 0u;
                }
            }
        }
        __syncthreads();
        // gather my row's 128 chunk keys at jperm positions (<=2-way banks)
        {
            const unsigned* rp = stg + (c & 1) * (cTI * cSTR) + wv * cSTR;
            #pragma unroll
            for (int jj = 0; jj < 2; ++jj) {
                const int j = (c << 7) + (jj << 6) + jperm;
                const unsigned kr = rp[(jj << 6) + jperm];
                key[(c << 1) + jj] = (j <= i) ? kr : 0u;
            }
        }
        // double buffer: next chunk stores to the other half; its barrier
        // orders those stores after this chunk's reads.
    }
    __syncthreads();   // staging dead; kl/jl lists may now clobber it

    // ---- Phase 2: per-row exact top-k + softmax + PV (1 row per wave) -----
    const int nb = (i >> 6) + 1;
    unsigned* kl = klA + wv * cLSZ;
    int*      jl = jlA + wv * cLSZ;
    const int vbase0 = (int)(((unsigned)bS * cKVH + kvh) * cDH);

    // row max + min over valid keys (valid keys are never 0)
    unsigned um = 0u, un = 0xFFFFFFFFu;
    #pragma unroll
    for (int jb = 0; jb < cNB; ++jb) {
        if (jb >= nb) break;
        const unsigned kk = key[jb];
        um = max(um, kk);
        un = min(un, kk ? kk : 0xFFFFFFFFu);
    }
    #pragma unroll
    for (int off = 32; off >= 1; off >>= 1) {
        um = max(um, (unsigned)__shfl_xor((int)um, off));
        un = min(un, (unsigned)__shfl_xor((int)un, off));
    }
    const float mrow = funmap(um);

    // exact 128th-largest key.  Bisection in [un, um] with early exit:
    // if count(>=mid) == 128 exactly, threshold = min{key >= mid} (the 128
    // counted keys are precisely the top-128; their min is the 128th value,
    // and no tie can exist outside the set since any key == thr >= mid is
    // counted).  Rows with i < 128 keep everything: ustar = un.
    unsigned ustar;
    if (i < cTOPK) {
        ustar = un;
    } else {
        unsigned lo = un, hi = um;
        while (lo < hi) {
            const unsigned d   = hi - lo;
            const unsigned mid = lo + (d >> 1) + (d & 1u);
            int cnt2 = 0;
            #pragma unroll
            for (int jb = 0; jb < cNB; ++jb) {
                if (jb >= nb) break;
                cnt2 += __popcll(__ballot(key[jb] >= mid));
            }
            if (cnt2 == cTOPK) {
                unsigned mn = 0xFFFFFFFFu;
                #pragma unroll
                for (int jb = 0; jb < cNB; ++jb) {
                    if (jb >= nb) break;
                    const unsigned kk = key[jb];
                    mn = min(mn, (kk >= mid) ? kk : 0xFFFFFFFFu);
                }
                #pragma unroll
                for (int off = 32; off >= 1; off >>= 1)
                    mn = min(mn, (unsigned)__shfl_xor((int)mn, off));
                lo = mn;
                break;
            }
            if (cnt2 > cTOPK) lo = mid; else hi = mid - 1u;
        }
        ustar = lo;
    }

    // ballot-prefix compaction of kept (j, key) into LDS
    const unsigned long long mlt = (1ull << lane) - 1ull;
    int base = 0;
    #pragma unroll
    for (int jb = 0; jb < cNB; ++jb) {
        if (jb >= nb) break;
        const int j = (jb << 6) + jperm;
        const bool keep = (j <= i) && (key[jb] >= ustar);
        const unsigned long long mk = __ballot(keep);
        const int pos = base + __popcll(mk & mlt);
        if (keep && pos < cLSZ) {
            kl[pos] = key[jb];
            jl[pos] = vbase0 + j * (cKVH * cDH);   // v element offset
        }
        base += __popcll(mk);
    }
    const int cnt = min(base, cLSZ);

    // weights + Z
    float zp = 0.f;
    for (int t = lane; t < cnt; t += 64) {
        const float s  = funmap(kl[t]);
        const float wt = __expf(s - mrow);
        ((float*)kl)[t] = wt;
        zp += wt;
    }
    #pragma unroll
    for (int off = 32; off >= 1; off >>= 1) zp += __shfl_xor(zp, off);
    const float invZ = 1.0f / zp;

    // PV: lane = d, f16 v, 8 independent accumulator chains, unroll 2 so
    // 16 v-loads issue per body (R12-proven load overlap).
    float ac0 = 0.f, ac1 = 0.f, ac2 = 0.f, ac3 = 0.f;
    float ac4 = 0.f, ac5 = 0.f, ac6 = 0.f, ac7 = 0.f;
    int t = 0;
    #pragma unroll 2
    for (; t + 7 < cnt; t += 8) {
        const float wt0 = ((float*)kl)[t];
        const float wt1 = ((float*)kl)[t + 1];
        const float wt2 = ((float*)kl)[t + 2];
        const float wt3 = ((float*)kl)[t + 3];
        const float wt4 = ((float*)kl)[t + 4];
        const float wt5 = ((float*)kl)[t + 5];
        const float wt6 = ((float*)kl)[t + 6];
        const float wt7 = ((float*)kl)[t + 7];
        const int vo0 = jl[t];
        const int vo1 = jl[t + 1];
        const int vo2 = jl[t + 2];
        const int vo3 = jl[t + 3];
        const int vo4 = jl[t + 4];
        const int vo5 = jl[t + 5];
        const int vo6 = jl[t + 6];
        const int vo7 = jl[t + 7];
        ac0 += wt0 * (float)__builtin_bit_cast(_Float16, vf[vo0 + lane]);
        ac1 += wt1 * (float)__builtin_bit_cast(_Float16, vf[vo1 + lane]);
        ac2 += wt2 * (float)__builtin_bit_cast(_Float16, vf[vo2 + lane]);
        ac3 += wt3 * (float)__builtin_bit_cast(_Float16, vf[vo3 + lane]);
        ac4 += wt4 * (float)__builtin_bit_cast(_Float16, vf[vo4 + lane]);
        ac5 += wt5 * (float)__builtin_bit_cast(_Float16, vf[vo5 + lane]);
        ac6 += wt6 * (float)__builtin_bit_cast(_Float16, vf[vo6 + lane]);
        ac7 += wt7 * (float)__builtin_bit_cast(_Float16, vf[vo7 + lane]);
    }
    for (; t < cnt; ++t) {
        const float wt = ((float*)kl)[t];
        const int   vo = jl[t];
        ac0 += wt * (float)__builtin_bit_cast(_Float16, vf[vo + lane]);
    }
    const float acc = ((ac0 + ac1) + (ac2 + ac3)) + ((ac4 + ac5) + (ac6 + ac7));
    out[((bS + i) * cQH + h) * cDH + lane] = f2bf(acc * invZ);
}

// ---------------------------------------------------------------------------
// Launch
// ---------------------------------------------------------------------------
extern "C" void kernel_launch(void* const* d_in, const int* in_sizes, int n_in,
                              void* d_out, int out_size, void* d_ws, size_t ws_size,
                              hipStream_t stream) {
    const float* x  = (const float*)d_in[0];
    const float* Wq = (const float*)d_in[1];
    const float* Wk = (const float*)d_in[2];
    const float* Wv = (const float*)d_in[3];
    const float* Wo = (const float*)d_in[4];
    float* out = (float*)d_out;

    float* ws = (float*)d_ws;
    float*  qb  = ws;                                   // 4M f32 (B,S,QH,DH)
    float*  kb  = qb + (size_t)cM * cQH * cDH;          // 1M f32
    float*  vb  = kb + (size_t)cM * cKVH * cDH;         // 1M f32
    ushort* xh  = (ushort*)(vb + (size_t)cM * cKVH * cDH);  // 4M bf16
    ushort* Wqh = xh  + (size_t)cM * cD;                // 1M bf16
    ushort* Wkh = Wqh + (size_t)cQH * cDH * cD;         // 256K bf16
    ushort* Wvh = Wkh + (size_t)cKVH * cDH * cD;        // 256K bf16
    ushort* Woh = Wvh + (size_t)cKVH * cDH * cD;        // 1M bf16
    ushort* abh = Woh + (size_t)cD * cQH * cDH;         // 4M bf16
    ushort* kff = abh + (size_t)cM * cQH * cDH;         // 1M f16 (roped k)
    ushort* qff = kff + (size_t)cM * cKVH * cDH;        // 4M f16 (roped q/8)
    // f16 v aliased into kb's fp32 slot (kb is dead after its rope_cast)
    ushort* vff = (ushort*)kb;                          // 1M f16

    dim3 blk(256);

    // casts to bf16 (GEMM inputs)
    {
        const int nx  = cM * cD;
        const int nwq = cQH * cDH * cD;
        const int nwk = cKVH * cDH * cD;
        const int nwo = cD * cQH * cDH;
        cast_f32_bf16<<<(nx / 4 + 255) / 256, blk, 0, stream>>>(x, xh, nx);
        cast_f32_bf16<<<(nwq / 4 + 255) / 256, blk, 0, stream>>>(Wq, Wqh, nwq);
        cast_f32_bf16<<<(nwk / 4 + 255) / 256, blk, 0, stream>>>(Wk, Wkh, nwk);
        cast_f32_bf16<<<(nwk / 4 + 255) / 256, blk, 0, stream>>>(Wv, Wvh, nwk);
        cast_f32_bf16<<<(nwo / 4 + 255) / 256, blk, 0, stream>>>(Wo, Woh, nwo);
    }

    // QKV projections (bf16 MFMA, fp32 out)
    gemm_bf16_bt<<<dim3((cQH * cDH) / 128, cM / 128), blk, 0, stream>>>(xh, Wqh, qb, cM, cQH * cDH, cD);
    gemm_bf16_bt<<<dim3((cKVH * cDH) / 128, cM / 128), blk, 0, stream>>>(xh, Wkh, kb, cM, cKVH * cDH, cD);
    gemm_bf16_bt<<<dim3((cKVH * cDH) / 128, cM / 128), blk, 0, stream>>>(xh, Wvh, vb, cM, cKVH * cDH, cD);

    // Fused RoPE + cast to f16 (q pre-scaled by 1/sqrt(DH)); v cast to f16.
    // NOTE: v cast runs after k's rope_cast so reusing kb's space is safe
    // (same stream => ordered).
    {
        int totq = cM * cQH * 32;
        int totk = cM * cKVH * 32;
        rope_cast_f16<<<(totq + 255) / 256, blk, 0, stream>>>(qb, qff, cQH, totq, 0.125f);
        rope_cast_f16<<<(totk + 255) / 256, blk, 0, stream>>>(kb, kff, cKVH, totk, 1.0f);
        const int nv = cM * cKVH * cDH;
        cast_f32_f16<<<(nv / 4 + 255) / 256, blk, 0, stream>>>(vb, vff, nv);
    }

    // Attention: MFMA chunked-transpose kernel, 512 threads, 24 KB LDS
    // (lists 8*384*8 = 24576 B; staging 2*8*130*4 = 8320 B aliases them).
    constexpr size_t aSMEM = (size_t)cTI * cLSZ * 8;    // 24576 B
    static_assert(2 * cTI * cSTR * 4 <= (int)aSMEM, "staging must fit");
    attn_tile_kernel<<<dim3(32 * (cS / cTI)), dim3(512), aSMEM, stream>>>(
        qff, kff, vff, abh);

    // Output projection (bf16 MFMA, fp32 out)
    gemm_bf16_bt<<<dim3(cD / 128, cM / 128), blk, 0, stream>>>(abh, Woh, out, cM, cD, cD);
}